// Round 8
// baseline (1364.978 us; speedup 1.0000x reference)
//
#include <hip/hip_runtime.h>
#include <hip/hip_bf16.h>

typedef __bf16 bf16x8 __attribute__((ext_vector_type(8)));
typedef float f32x4 __attribute__((ext_vector_type(4)));

__device__ __forceinline__ void gload16(const void* g, void* l) {
  __builtin_amdgcn_global_load_lds(
      (const __attribute__((address_space(1))) void*)g,
      (__attribute__((address_space(3))) void*)l, 16, 0, 0);
}

__device__ __forceinline__ unsigned short f2bf(float f) {
  __hip_bfloat16 h = __float2bfloat16(f);
  union { __hip_bfloat16 h; unsigned short u; } c;
  c.h = h;
  return c.u;
}

__device__ __forceinline__ void fwht16(float v[16]) {
#pragma unroll
  for (int s = 1; s < 16; s <<= 1) {
#pragma unroll
    for (int i = 0; i < 16; i++) {
      if ((i & s) == 0) {
        float a = v[i], b = v[i | s];
        v[i] = a + b;
        v[i | s] = a - b;
      }
    }
  }
}

// ---------------- FWHT #1: h1 = bf16( fwht(x*SU) / 2048 ) ----------------
__global__ __launch_bounds__(256) void fwht1_kernel(
    const float* __restrict__ x, const float* __restrict__ SU,
    unsigned short* __restrict__ H1) {
  __shared__ float lds[256 * 17];
  const int t = threadIdx.x;
  const size_t row = blockIdx.x;
  const float* xr = x + row * 4096;
  float v[16];
#pragma unroll
  for (int n2 = 0; n2 < 16; n2++) {
    int n = n2 * 256 + t;
    v[n2] = xr[n] * SU[n];
  }
  fwht16(v);
  const int n1 = t >> 4, n0 = t & 15;
#pragma unroll
  for (int j2 = 0; j2 < 16; j2++) lds[(j2 * 16 + n1) * 17 + n0] = v[j2];
  __syncthreads();
#pragma unroll
  for (int k = 0; k < 16; k++) v[k] = lds[((t >> 4) * 16 + k) * 17 + (t & 15)];
  fwht16(v);
#pragma unroll
  for (int k = 0; k < 16; k++) lds[((t >> 4) * 16 + k) * 17 + (t & 15)] = v[k];
  __syncthreads();
#pragma unroll
  for (int k = 0; k < 16; k++) v[k] = lds[t * 17 + k];
  fwht16(v);
  const float cst = 1.0f / 2048.0f;
  union { unsigned short u[16]; uint4 q[2]; } o;
#pragma unroll
  for (int k = 0; k < 16; k++) o.u[k] = f2bf(v[k] * cst);
  uint4* dst = (uint4*)(H1 + row * 4096 + (size_t)t * 16);
  dst[0] = o.q[0];
  dst[1] = o.q[1];
}

// ---------------- W conversion: Wb[m][n] = bf16(W[m][n] * Wscale[m]) -------
__global__ __launch_bounds__(256) void convw_kernel(
    const float4* __restrict__ W4, const float* __restrict__ Wscale,
    uint2* __restrict__ Wb4, int total4, int Nq) {
  int i = blockIdx.x * 256 + threadIdx.x;
  if (i >= total4) return;
  float4 w = W4[i];
  float s = Wscale[i / Nq];
  unsigned int lo = (unsigned)f2bf(w.x * s) | ((unsigned)f2bf(w.y * s) << 16);
  unsigned int hi = (unsigned)f2bf(w.z * s) | ((unsigned)f2bf(w.w * s) << 16);
  Wb4[i] = make_uint2(lo, hi);
}

// ---------------- GEMM (R6 schedule) + ablation MODEs ----------------------
// MODE 0: real (full grid, writes C).            DO_STAGE DO_READ
// MODE 4: control, small grid -> scratch.        DO_STAGE DO_READ
// MODE 1: noSTAGE (LDS pre-staged; no gloads).            DO_READ
// MODE 2: noDSREAD (const frags).                DO_STAGE
// MODE 3: mfmaOnly (barriers+setprio+MFMA).
// All keep the identical barrier/setprio skeleton; acc kept live via C-write.

#define BAR() __builtin_amdgcn_s_barrier()
#define SCHED() __builtin_amdgcn_sched_barrier(0)
#define GATE2()                              \
  do {                                       \
    SCHED();                                 \
    asm volatile("s_waitcnt vmcnt(2)");      \
    SCHED();                                 \
  } while (0)
#define GATE0()                              \
  do {                                       \
    SCHED();                                 \
    asm volatile("s_waitcnt vmcnt(0)");      \
    SCHED();                                 \
  } while (0)
#define LGKM0() asm volatile("s_waitcnt lgkmcnt(0)")
#define LGKM8() asm volatile("s_waitcnt lgkmcnt(8)")

__device__ __forceinline__ void stage_half(const unsigned short* __restrict__ g,
                                           unsigned short* l, int tid, int K) {
#pragma unroll
  for (int i = 0; i < 2; i++) {
    int idx = i * 512 + tid;
    int r = idx >> 3;
    int c = (idx & 7) ^ (r & 7);
    gload16(g + (size_t)r * K + c * 8, l + idx * 8);
  }
}

#define STAGE_A(d, hh, kt) \
  stage_half(Abase + (size_t)(hh)*128 * K + (size_t)(kt)*64, &As[d][(hh)*8192], tid, K)
#define STAGE_B(d, hh, kt) \
  stage_half(Bbase + (size_t)(hh)*128 * K + (size_t)(kt)*64, &Bs[d][(hh)*8192], tid, K)

#define LOAD_A(d, m)                                                          \
  {                                                                           \
    _Pragma("unroll") for (int i = 0; i < 4; i++) {                           \
      _Pragma("unroll") for (int ks = 0; ks < 2; ks++) {                      \
        int r = wm * 128 + (m)*64 + i * 16 + fr;                              \
        int kc = ks * 4 + lhi;                                                \
        ah[i][ks] = *(const bf16x8*)&As[d][r * 64 + ((kc ^ (r & 7)) << 3)];   \
      }                                                                       \
    }                                                                         \
  }

#define LOAD_B(d, v, dst)                                                     \
  {                                                                           \
    _Pragma("unroll") for (int j = 0; j < 2; j++) {                           \
      _Pragma("unroll") for (int ks = 0; ks < 2; ks++) {                      \
        int r = wn * 64 + (v)*32 + j * 16 + fr;                               \
        int kc = ks * 4 + lhi;                                                \
        dst[j][ks] = *(const bf16x8*)&Bs[d][r * 64 + ((kc ^ (r & 7)) << 3)];  \
      }                                                                       \
    }                                                                         \
  }

#define MFMA_PH(m, v, bvx)                                                    \
  {                                                                           \
    __builtin_amdgcn_s_setprio(1);                                            \
    _Pragma("unroll") for (int i = 0; i < 4; i++)                             \
      _Pragma("unroll") for (int j = 0; j < 2; j++)                           \
        _Pragma("unroll") for (int ks = 0; ks < 2; ks++)                      \
          acc[(m)*4 + i][(v)*2 + j] = __builtin_amdgcn_mfma_f32_16x16x32_bf16( \
              ah[i][ks], bvx[j][ks], acc[(m)*4 + i][(v)*2 + j], 0, 0, 0);     \
    __builtin_amdgcn_s_setprio(0);                                            \
  }

template <int MODE>
__global__ __launch_bounds__(512, 2) void gemm8_kernel(
    const unsigned short* __restrict__ A, const unsigned short* __restrict__ B,
    float* __restrict__ C, float* __restrict__ Cs, int M, int K, int NT) {
  constexpr bool DO_STAGE = (MODE == 0 || MODE == 4 || MODE == 2);
  constexpr bool DO_READ = (MODE == 0 || MODE == 4 || MODE == 1);
  __shared__ __align__(16) unsigned short As[2][256 * 64];
  __shared__ __align__(16) unsigned short Bs[2][256 * 64];
  const int nbn = M >> 8;
  const int cpx = gridDim.x >> 3;
  int bid = blockIdx.x;
  bid = (bid & 7) * cpx + (bid >> 3);  // XCD swizzle (grid % 8 == 0)
  const int brow = (bid / nbn) << 8;
  const int bcol = (bid % nbn) << 8;
  const int tid = threadIdx.x;
  const int lane = tid & 63;
  const int w = tid >> 6;
  const int wm = w >> 2;
  const int wn = w & 3;
  const int fr = lane & 15;
  const int lhi = lane >> 4;

  const unsigned short* Abase = A + (size_t)brow * K;
  const unsigned short* Bbase = B + (size_t)bcol * K;

  f32x4 acc[8][4];
#pragma unroll
  for (int i = 0; i < 8; i++)
#pragma unroll
    for (int j = 0; j < 4; j++) acc[i][j] = (f32x4){0.f, 0.f, 0.f, 0.f};
  bf16x8 ah[4][2], bv0[2][2], bv1[2][2];
#pragma unroll
  for (int i = 0; i < 4; i++)
#pragma unroll
    for (int ks = 0; ks < 2; ks++) ah[i][ks] = (bf16x8){};
#pragma unroll
  for (int j = 0; j < 2; j++)
#pragma unroll
    for (int ks = 0; ks < 2; ks++) { bv0[j][ks] = (bf16x8){}; bv1[j][ks] = (bf16x8){}; }

  // Prologue
  if constexpr (MODE == 0 || MODE == 4 || MODE == 2) {
    STAGE_A(0, 0, 0);
    STAGE_A(0, 1, 0);
    STAGE_B(0, 0, 0);
    STAGE_B(0, 1, 0);
    STAGE_A(1, 0, 1);
    GATE2();
  } else if constexpr (MODE == 1) {
    // Pre-stage ALL of both buffers deterministically (no loads in loop).
    STAGE_A(0, 0, 0);
    STAGE_A(0, 1, 0);
    STAGE_B(0, 0, 0);
    STAGE_B(0, 1, 0);
    STAGE_A(1, 0, 1);
    STAGE_A(1, 1, 1);
    STAGE_B(1, 0, 1);
    STAGE_B(1, 1, 1);
    GATE0();
  }
  BAR();

  const int NTT = NT / 2;
#pragma unroll 1
  for (int t = 0; t < NTT; ++t) {
    const bool last = (t == NTT - 1);
    const int u1 = 2 * t + 1, u2 = 2 * t + 2, u3 = 2 * t + 3;
    // P1
    if constexpr (DO_READ) {
      LOAD_A(0, 0);
      LOAD_B(0, 0, bv0);
    }
    if constexpr (DO_STAGE) STAGE_A(1, 1, u1);
    if constexpr (DO_READ) LGKM8();
    BAR();
    LGKM0();
    MFMA_PH(0, 0, bv0);
    BAR();
    // P2
    if constexpr (DO_READ) LOAD_B(0, 1, bv1);
    if constexpr (DO_STAGE) STAGE_B(1, 0, u1);
    BAR();
    LGKM0();
    MFMA_PH(0, 1, bv1);
    BAR();
    // P3
    if constexpr (DO_READ) LOAD_A(0, 1);
    if constexpr (DO_STAGE) STAGE_B(1, 1, u1);
    BAR();
    LGKM0();
    MFMA_PH(1, 1, bv1);
    BAR();
    // P4
    if constexpr (DO_STAGE) {
      if (!last) {
        STAGE_A(0, 0, u2);
        GATE2();
      } else {
        GATE0();
      }
    }
    BAR();
    MFMA_PH(1, 0, bv0);
    BAR();
    // P5
    if constexpr (DO_READ) {
      LOAD_A(1, 0);
      LOAD_B(1, 0, bv0);
    }
    if constexpr (DO_STAGE) {
      if (!last) STAGE_A(0, 1, u2);
    }
    if constexpr (DO_READ) LGKM8();
    BAR();
    LGKM0();
    MFMA_PH(0, 0, bv0);
    BAR();
    // P6
    if constexpr (DO_READ) LOAD_B(1, 1, bv1);
    if constexpr (DO_STAGE) {
      if (!last) STAGE_B(0, 0, u2);
    }
    BAR();
    LGKM0();
    MFMA_PH(0, 1, bv1);
    BAR();
    // P7
    if constexpr (DO_READ) LOAD_A(1, 1);
    if constexpr (DO_STAGE) {
      if (!last) STAGE_B(0, 1, u2);
    }
    BAR();
    LGKM0();
    MFMA_PH(1, 1, bv1);
    BAR();
    // P8
    if constexpr (DO_STAGE) {
      if (!last) {
        STAGE_A(1, 0, u3);
        GATE2();
      }
    }
    BAR();
    MFMA_PH(1, 0, bv0);
    BAR();
  }

  // Epilogue
  const int lr0 = wm * 128 + lhi * 4;
  const int lc0 = wn * 64 + fr;
  if constexpr (MODE == 0) {
    const int crow0 = brow + lr0;
    const int ccol0 = bcol + lc0;
#pragma unroll
    for (int mi = 0; mi < 8; mi++)
#pragma unroll
      for (int nj = 0; nj < 4; nj++)
#pragma unroll
        for (int q = 0; q < 4; q++)
          C[(size_t)(crow0 + mi * 16 + q) * M + ccol0 + nj * 16] =
              acc[mi][nj][q];
  } else {
    float* Cw = Cs + (size_t)blockIdx.x * 65536;
#pragma unroll
    for (int mi = 0; mi < 8; mi++)
#pragma unroll
      for (int nj = 0; nj < 4; nj++)
#pragma unroll
        for (int q = 0; q < 4; q++)
          Cw[(size_t)(lr0 + mi * 16 + q) * 256 + lc0 + nj * 16] =
              acc[mi][nj][q];
  }
}

// ---------------- FWHT #2 (in-place on d_out): out = fwht(Y)*0.5*SV ------
__global__ __launch_bounds__(256) void fwht2_kernel(
    float* __restrict__ Y, const float* __restrict__ SV) {
  __shared__ float lds[256 * 17];
  const int t = threadIdx.x;
  const size_t row = blockIdx.x;
  float* yr = Y + row * 4096;
  float v[16];
#pragma unroll
  for (int n2 = 0; n2 < 16; n2++) v[n2] = yr[n2 * 256 + t];
  fwht16(v);
  const int n1 = t >> 4, n0 = t & 15;
#pragma unroll
  for (int j2 = 0; j2 < 16; j2++) lds[(j2 * 16 + n1) * 17 + n0] = v[j2];
  __syncthreads();
#pragma unroll
  for (int k = 0; k < 16; k++) v[k] = lds[((t >> 4) * 16 + k) * 17 + (t & 15)];
  fwht16(v);
#pragma unroll
  for (int k = 0; k < 16; k++) lds[((t >> 4) * 16 + k) * 17 + (t & 15)] = v[k];
  __syncthreads();
#pragma unroll
  for (int k = 0; k < 16; k++) v[k] = lds[t * 17 + k];
  fwht16(v);
  float outv[16];
#pragma unroll
  for (int k = 0; k < 16; k++) outv[k] = v[k] * 0.5f * SV[(size_t)t * 16 + k];
  float4* dst = (float4*)(yr + (size_t)t * 16);
#pragma unroll
  for (int k = 0; k < 4; k++)
    dst[k] = make_float4(outv[4 * k], outv[4 * k + 1], outv[4 * k + 2],
                         outv[4 * k + 3]);
}

extern "C" void kernel_launch(void* const* d_in, const int* in_sizes, int n_in,
                              void* d_out, int out_size, void* d_ws,
                              size_t ws_size, hipStream_t stream) {
  const float* x = (const float*)d_in[0];
  const float* W = (const float*)d_in[1];
  const float* SU = (const float*)d_in[2];
  const float* SV = (const float*)d_in[3];
  const float* Wscale = (const float*)d_in[4];
  const int N = in_sizes[2];      // 4096
  const int M = in_sizes[3];      // 4096
  const int T = in_sizes[0] / N;  // 16384

  unsigned short* H1 = (unsigned short*)d_ws;
  unsigned short* Wb = H1 + (size_t)T * N;
  float* out = (float*)d_out;

  fwht1_kernel<<<T, 256, 0, stream>>>(x, SU, H1);
  const int total4 = (int)(((long)M * N) / 4);
  convw_kernel<<<(total4 + 255) / 256, 256, 0, stream>>>(
      (const float4*)W, Wscale, (uint2*)Wb, total4, N / 4);
  const int NT = N / 64;
  gemm8_kernel<0><<<(T / 256) * (M / 256), 512, 0, stream>>>(
      H1, Wb, out, nullptr, M, N, NT);
  fwht2_kernel<<<T, 256, 0, stream>>>(out, SV);

  // ---- Ablation probes (scratch-writing, after the timed-path kernels) ----
  const size_t usedB = ((size_t)T * N + (size_t)M * N) * sizeof(unsigned short);
  const size_t scrB = (size_t)256 * 65536 * sizeof(float);  // 64 MB
  if (ws_size >= usedB + scrB) {
    float* Cs = (float*)((char*)d_ws + usedB);
    // M4 control: full pipeline, 1 block/CU, NTT=32  (expect ~ real/4)
    gemm8_kernel<4><<<256, 512, 0, stream>>>(H1, Wb, nullptr, Cs, M, N, NT);
    // M1 noSTAGE: ds_read+MFMA only, NTT=64 (2x work; LDS pre-staged)
    gemm8_kernel<1><<<256, 512, 0, stream>>>(H1, Wb, nullptr, Cs, M, N, 2 * NT);
    // M2 noDSREAD: stage+vmcnt+MFMA, NTT=32
    gemm8_kernel<2><<<256, 512, 0, stream>>>(H1, Wb, nullptr, Cs, M, N, NT);
    // M3 mfmaOnly: barriers+setprio+MFMA, NTT=96 (3x work)
    gemm8_kernel<3><<<256, 512, 0, stream>>>(H1, Wb, nullptr, Cs, M, N, 3 * NT);
  }
}

// Round 9
// 809.171 us; speedup vs baseline: 1.6869x; 1.6869x over previous
//
#include <hip/hip_runtime.h>
#include <hip/hip_bf16.h>

typedef __bf16 bf16x8 __attribute__((ext_vector_type(8)));
typedef float f32x4 __attribute__((ext_vector_type(4)));

__device__ __forceinline__ void gload16(const void* g, void* l) {
  __builtin_amdgcn_global_load_lds(
      (const __attribute__((address_space(1))) void*)g,
      (__attribute__((address_space(3))) void*)l, 16, 0, 0);
}

__device__ __forceinline__ unsigned short f2bf(float f) {
  __hip_bfloat16 h = __float2bfloat16(f);
  union { __hip_bfloat16 h; unsigned short u; } c;
  c.h = h;
  return c.u;
}

__device__ __forceinline__ void fwht16(float v[16]) {
#pragma unroll
  for (int s = 1; s < 16; s <<= 1) {
#pragma unroll
    for (int i = 0; i < 16; i++) {
      if ((i & s) == 0) {
        float a = v[i], b = v[i | s];
        v[i] = a + b;
        v[i | s] = a - b;
      }
    }
  }
}

// ---------------- FWHT #1: h1 = bf16( fwht(x*SU) / 2048 ) ----------------
__global__ __launch_bounds__(256) void fwht1_kernel(
    const float* __restrict__ x, const float* __restrict__ SU,
    unsigned short* __restrict__ H1) {
  __shared__ float lds[256 * 17];
  const int t = threadIdx.x;
  const size_t row = blockIdx.x;
  const float* xr = x + row * 4096;
  float v[16];
#pragma unroll
  for (int n2 = 0; n2 < 16; n2++) {
    int n = n2 * 256 + t;
    v[n2] = xr[n] * SU[n];
  }
  fwht16(v);
  const int n1 = t >> 4, n0 = t & 15;
#pragma unroll
  for (int j2 = 0; j2 < 16; j2++) lds[(j2 * 16 + n1) * 17 + n0] = v[j2];
  __syncthreads();
#pragma unroll
  for (int k = 0; k < 16; k++) v[k] = lds[((t >> 4) * 16 + k) * 17 + (t & 15)];
  fwht16(v);
#pragma unroll
  for (int k = 0; k < 16; k++) lds[((t >> 4) * 16 + k) * 17 + (t & 15)] = v[k];
  __syncthreads();
#pragma unroll
  for (int k = 0; k < 16; k++) v[k] = lds[t * 17 + k];
  fwht16(v);
  const float cst = 1.0f / 2048.0f;
  union { unsigned short u[16]; uint4 q[2]; } o;
#pragma unroll
  for (int k = 0; k < 16; k++) o.u[k] = f2bf(v[k] * cst);
  uint4* dst = (uint4*)(H1 + row * 4096 + (size_t)t * 16);
  dst[0] = o.q[0];
  dst[1] = o.q[1];
}

// ---------------- W conversion: Wb[m][n] = bf16(W[m][n] * Wscale[m]) -------
__global__ __launch_bounds__(256) void convw_kernel(
    const float4* __restrict__ W4, const float* __restrict__ Wscale,
    uint2* __restrict__ Wb4, int total4, int Nq) {
  int i = blockIdx.x * 256 + threadIdx.x;
  if (i >= total4) return;
  float4 w = W4[i];
  float s = Wscale[i / Nq];
  unsigned int lo = (unsigned)f2bf(w.x * s) | ((unsigned)f2bf(w.y * s) << 16);
  unsigned int hi = (unsigned)f2bf(w.z * s) | ((unsigned)f2bf(w.w * s) << 16);
  Wb4[i] = make_uint2(lo, hi);
}

// ---------------- GEMM: 256x256, BK=64, 8 waves, fused-phase schedule ------
// Phase = { BAR; stage(2 gloads); ds_reads; MFMA } with NO lgkm fences:
// compiler emits counted lgkmcnt per consuming MFMA, so reads drain UNDER
// the MFMA cluster (max instead of sum). Single barrier/phase:
//  - WAR: every read is consumed by an in-phase MFMA, so reads complete
//    before the wave reaches the next BAR; restages issue only after it.
//  - RAW: vmcnt gates (SCHED-pinned, no clobbers) at end of P4/P8, one
//    barrier before the reads they protect. FIFO (2 loads/thread/phase):
//    at P4: outstanding {prevP8,P1,P2,P3,P4}=10, GATE2 drains 8 = buf about
//    to be read. Tail: P4 GATE0, stages skipped.
// MFMA accumulation ks-OUTER: dependent acc pairs separated by 8 indep MFMAs.

#define BAR() __builtin_amdgcn_s_barrier()
#define SCHED() __builtin_amdgcn_sched_barrier(0)
#define GATE2()                              \
  do {                                       \
    SCHED();                                 \
    asm volatile("s_waitcnt vmcnt(2)");      \
    SCHED();                                 \
  } while (0)
#define GATE0()                              \
  do {                                       \
    SCHED();                                 \
    asm volatile("s_waitcnt vmcnt(0)");      \
    SCHED();                                 \
  } while (0)

__device__ __forceinline__ void stage_half(const unsigned short* __restrict__ g,
                                           unsigned short* l, int tid, int K) {
#pragma unroll
  for (int i = 0; i < 2; i++) {
    int idx = i * 512 + tid;
    int r = idx >> 3;
    int c = (idx & 7) ^ (r & 7);
    gload16(g + (size_t)r * K + c * 8, l + idx * 8);
  }
}

#define STAGE_A(d, hh, kt) \
  stage_half(Abase + (size_t)(hh)*128 * K + (size_t)(kt)*64, &As[d][(hh)*8192], tid, K)
#define STAGE_B(d, hh, kt) \
  stage_half(Bbase + (size_t)(hh)*128 * K + (size_t)(kt)*64, &Bs[d][(hh)*8192], tid, K)

#define LOAD_A(d, m)                                                          \
  {                                                                           \
    _Pragma("unroll") for (int i = 0; i < 4; i++) {                           \
      _Pragma("unroll") for (int ks = 0; ks < 2; ks++) {                      \
        int r = wm * 128 + (m)*64 + i * 16 + fr;                              \
        int kc = ks * 4 + lhi;                                                \
        ah[i][ks] = *(const bf16x8*)&As[d][r * 64 + ((kc ^ (r & 7)) << 3)];   \
      }                                                                       \
    }                                                                         \
  }

#define LOAD_B(d, v, dst)                                                     \
  {                                                                           \
    _Pragma("unroll") for (int j = 0; j < 2; j++) {                           \
      _Pragma("unroll") for (int ks = 0; ks < 2; ks++) {                      \
        int r = wn * 64 + (v)*32 + j * 16 + fr;                               \
        int kc = ks * 4 + lhi;                                                \
        dst[j][ks] = *(const bf16x8*)&Bs[d][r * 64 + ((kc ^ (r & 7)) << 3)];  \
      }                                                                       \
    }                                                                         \
  }

// ks OUTER: 8 independent MFMAs between each dependent accumulate pair.
#define MFMA_PH(m, v, bvx)                                                    \
  {                                                                           \
    __builtin_amdgcn_s_setprio(1);                                            \
    _Pragma("unroll") for (int ks = 0; ks < 2; ks++)                          \
      _Pragma("unroll") for (int i = 0; i < 4; i++)                           \
        _Pragma("unroll") for (int j = 0; j < 2; j++)                         \
          acc[(m)*4 + i][(v)*2 + j] = __builtin_amdgcn_mfma_f32_16x16x32_bf16( \
              ah[i][ks], bvx[j][ks], acc[(m)*4 + i][(v)*2 + j], 0, 0, 0);     \
    __builtin_amdgcn_s_setprio(0);                                            \
  }

__global__ __launch_bounds__(512, 2) void gemm8_kernel(
    const unsigned short* __restrict__ A, const unsigned short* __restrict__ B,
    float* __restrict__ C, int M, int K, int NT) {
  __shared__ __align__(16) unsigned short As[2][256 * 64];
  __shared__ __align__(16) unsigned short Bs[2][256 * 64];
  const int nbn = M >> 8;
  const int cpx = gridDim.x >> 3;
  int bid = blockIdx.x;
  bid = (bid & 7) * cpx + (bid >> 3);  // XCD swizzle (grid % 8 == 0)
  const int brow = (bid / nbn) << 8;
  const int bcol = (bid % nbn) << 8;
  const int tid = threadIdx.x;
  const int lane = tid & 63;
  const int w = tid >> 6;  // 8 waves: 2 (M) x 4 (N)
  const int wm = w >> 2;
  const int wn = w & 3;
  const int fr = lane & 15;
  const int lhi = lane >> 4;

  const unsigned short* Abase = A + (size_t)brow * K;
  const unsigned short* Bbase = B + (size_t)bcol * K;

  f32x4 acc[8][4];
#pragma unroll
  for (int i = 0; i < 8; i++)
#pragma unroll
    for (int j = 0; j < 4; j++) acc[i][j] = (f32x4){0.f, 0.f, 0.f, 0.f};
  bf16x8 ah[4][2], bv0[2][2], bv1[2][2];

  // Prologue: b0 <- tile0 (A0,A1,B0,B1 = 8 loads); b1.A0 <- tile1 (2).
  // GATE2 drains b0's 8; P1's BAR separates gate from reads.
  STAGE_A(0, 0, 0);
  STAGE_A(0, 1, 0);
  STAGE_B(0, 0, 0);
  STAGE_B(0, 1, 0);
  STAGE_A(1, 0, 1);
  GATE2();

  const int NTT = NT / 2;
#pragma unroll 1
  for (int t = 0; t < NTT; ++t) {
    const bool last = (t == NTT - 1);
    const int u1 = 2 * t + 1, u2 = 2 * t + 2, u3 = 2 * t + 3;
    // P1: b0 reads A[m0]+B[n0] fused with MFMA; stage b1.A1 <- u1
    BAR();
    STAGE_A(1, 1, u1);
    LOAD_A(0, 0);
    LOAD_B(0, 0, bv0);
    MFMA_PH(0, 0, bv0);
    // P2: b0 B[n1]; stage b1.B0 <- u1
    BAR();
    STAGE_B(1, 0, u1);
    LOAD_B(0, 1, bv1);
    MFMA_PH(0, 1, bv1);
    // P3: b0 A[m1]; stage b1.B1 <- u1 (tile u1 fully issued)
    BAR();
    STAGE_B(1, 1, u1);
    LOAD_A(0, 1);
    MFMA_PH(1, 1, bv1);
    // P4: no reads (ah=m1, bv0 live); stage b0.A0 <- u2; gate b1 for P5
    BAR();
    if (!last) STAGE_A(0, 0, u2);
    MFMA_PH(1, 0, bv0);
    if (!last) { GATE2(); } else { GATE0(); }
    // P5: b1 reads A[m0]+B[n0]; stage b0.A1 <- u2
    BAR();
    if (!last) STAGE_A(0, 1, u2);
    LOAD_A(1, 0);
    LOAD_B(1, 0, bv0);
    MFMA_PH(0, 0, bv0);
    // P6: b1 B[n1]; stage b0.B0 <- u2
    BAR();
    if (!last) STAGE_B(0, 0, u2);
    LOAD_B(1, 1, bv1);
    MFMA_PH(0, 1, bv1);
    // P7: b1 A[m1]; stage b0.B1 <- u2 (tile u2 fully issued)
    BAR();
    if (!last) STAGE_B(0, 1, u2);
    LOAD_A(1, 1);
    MFMA_PH(1, 1, bv1);
    // P8: no reads; stage b1.A0 <- u3; gate b0 for P1'
    BAR();
    if (!last) STAGE_A(1, 0, u3);
    MFMA_PH(1, 0, bv0);
    if (!last) GATE2();
  }

  // Epilogue: C/D layout col=lane&15, row=(lane>>4)*4+q  [m89-verified]
  const int crow0 = brow + wm * 128 + lhi * 4;
  const int ccol0 = bcol + wn * 64 + fr;
#pragma unroll
  for (int mi = 0; mi < 8; mi++)
#pragma unroll
    for (int nj = 0; nj < 4; nj++)
#pragma unroll
      for (int q = 0; q < 4; q++)
        C[(size_t)(crow0 + mi * 16 + q) * M + ccol0 + nj * 16] = acc[mi][nj][q];
}

// ---------------- FWHT #2 (in-place on d_out): out = fwht(Y)*0.5*SV ------
__global__ __launch_bounds__(256) void fwht2_kernel(
    float* __restrict__ Y, const float* __restrict__ SV) {
  __shared__ float lds[256 * 17];
  const int t = threadIdx.x;
  const size_t row = blockIdx.x;
  float* yr = Y + row * 4096;
  float v[16];
#pragma unroll
  for (int n2 = 0; n2 < 16; n2++) v[n2] = yr[n2 * 256 + t];
  fwht16(v);
  const int n1 = t >> 4, n0 = t & 15;
#pragma unroll
  for (int j2 = 0; j2 < 16; j2++) lds[(j2 * 16 + n1) * 17 + n0] = v[j2];
  __syncthreads();
#pragma unroll
  for (int k = 0; k < 16; k++) v[k] = lds[((t >> 4) * 16 + k) * 17 + (t & 15)];
  fwht16(v);
#pragma unroll
  for (int k = 0; k < 16; k++) lds[((t >> 4) * 16 + k) * 17 + (t & 15)] = v[k];
  __syncthreads();
#pragma unroll
  for (int k = 0; k < 16; k++) v[k] = lds[t * 17 + k];
  fwht16(v);
  float outv[16];
#pragma unroll
  for (int k = 0; k < 16; k++) outv[k] = v[k] * 0.5f * SV[(size_t)t * 16 + k];
  float4* dst = (float4*)(yr + (size_t)t * 16);
#pragma unroll
  for (int k = 0; k < 4; k++)
    dst[k] = make_float4(outv[4 * k], outv[4 * k + 1], outv[4 * k + 2],
                         outv[4 * k + 3]);
}

extern "C" void kernel_launch(void* const* d_in, const int* in_sizes, int n_in,
                              void* d_out, int out_size, void* d_ws,
                              size_t ws_size, hipStream_t stream) {
  const float* x = (const float*)d_in[0];
  const float* W = (const float*)d_in[1];
  const float* SU = (const float*)d_in[2];
  const float* SV = (const float*)d_in[3];
  const float* Wscale = (const float*)d_in[4];
  const int N = in_sizes[2];      // 4096
  const int M = in_sizes[3];      // 4096
  const int T = in_sizes[0] / N;  // 16384

  unsigned short* H1 = (unsigned short*)d_ws;
  unsigned short* Wb = H1 + (size_t)T * N;
  float* out = (float*)d_out;

  fwht1_kernel<<<T, 256, 0, stream>>>(x, SU, H1);
  const int total4 = (int)(((long)M * N) / 4);
  convw_kernel<<<(total4 + 255) / 256, 256, 0, stream>>>(
      (const float4*)W, Wscale, (uint2*)Wb, total4, N / 4);
  const int NT = N / 64;  // 64 K-tiles
  gemm8_kernel<<<(T / 256) * (M / 256), 512, 0, stream>>>(H1, Wb, out, M, N, NT);
  fwht2_kernel<<<T, 256, 0, stream>>>(out, SV);
}